// Round 3
// baseline (42.713 us; speedup 1.0000x reference)
//
#include <hip/hip_runtime.h>

// Problem constants
#define BB     4096
#define NNODE  177
#define NSUB   36
#define KN     6
#define HH     128
#define OBSD   500
#define TB     16          // batches per block (= MFMA M, all rows real)
#define NTHR   576         // 9 waves: 8 h-col tiles + 1 e-tile

typedef unsigned short ushort_t;
typedef __attribute__((ext_vector_type(4))) float f32x4;
typedef __attribute__((ext_vector_type(8))) short s16x8;
typedef __attribute__((ext_vector_type(4))) unsigned short u16x4;

#define MFMA16(a, b, c) __builtin_amdgcn_mfma_f32_16x16x32_bf16((a), (b), (c), 0, 0, 0)

// ws layout (bytes)
#define WS_WPROJT 0          // ushort[128][512]  = 131072
#define WS_W1T    131072     // ushort[128][384]  =  98304
#define WS_BEOBS  229376     // ushort[16][512]   =  16384 (rows 8..15 zero)
#define WS_BESUB  245760     // ushort[16][128]   =   4096 (rows 8..15 zero)
#define WS_BENODE 249856     // ushort[16][128]   =   4096 (rows 8..15 zero)
#define WS_BIASE  253952     // float[16]         (8..15 zero)

__device__ __forceinline__ ushort_t f2bf(float f) {
    unsigned u = __float_as_uint(f);
    u += 0x7FFFu + ((u >> 16) & 1u);   // RNE
    return (ushort_t)(u >> 16);
}
__device__ __forceinline__ u16x4 f2bf4(float4 v) {
    u16x4 o; o.x = f2bf(v.x); o.y = f2bf(v.y); o.z = f2bf(v.z); o.w = f2bf(v.w);
    return o;
}

// ---------------------------------------------------------------------------
// Prep: pure transpose/convert + tiny e-fold arrays. No big GEMM.
//  WprojT[c][k] (k<500 = Wproj^T, else 0), W1T[c][i] = W1^T (i<384),
//  BeObs[e][k] = Wproj @ (W1a-fold with a-vec), BeSub/BeNode = W1b/W1c folds,
//  biasE[e] = bproj @ W1a-fold.  e<4: src head e; e>=4: dst head e-4.
// ---------------------------------------------------------------------------
__global__ void __launch_bounds__(256) k_prep(const float* __restrict__ Wproj,
                                              const float* __restrict__ bproj,
                                              const float* __restrict__ W1,
                                              const float* __restrict__ a_src1,
                                              const float* __restrict__ a_dst1,
                                              ushort_t* __restrict__ WprojT,
                                              ushort_t* __restrict__ W1T,
                                              ushort_t* __restrict__ BeObs,
                                              ushort_t* __restrict__ BeSub,
                                              ushort_t* __restrict__ BeNode,
                                              float* __restrict__ biasE) {
    const int blk = blockIdx.x, t = threadIdx.x;
    if (blk < 256) {                       // WprojT: 128x512
        int o = blk * 256 + t;
        int c = o & 127, k = o >> 7;
        WprojT[c * 512 + k] = (k < 500) ? f2bf(Wproj[k * 128 + c]) : (ushort_t)0;
    } else if (blk < 448) {                // W1T: 128x384
        int o = (blk - 256) * 256 + t;
        int c = o & 127, i = o >> 7;
        W1T[c * 384 + i] = f2bf(W1[i * 128 + c]);
    } else if (blk < 464) {                // BeObs rows 0..7 (k-chunk per block)
        __shared__ float s_f[128][8];
        for (int it = t; it < 1024; it += 256) {
            int i = it >> 3, e = it & 7, hd = e & 3;
            const float* av = ((e < 4) ? a_src1 : a_dst1) + hd * 32;
            float acc = 0.f;
            #pragma unroll
            for (int f = 0; f < 32; ++f) acc += W1[i * 128 + hd * 32 + f] * av[f];
            s_f[i][e] = acc;
        }
        __syncthreads();
        int e = t >> 5, k = (blk - 448) * 32 + (t & 31);
        float acc = 0.f;
        if (k < 500) {
            const float4* wr = (const float4*)(Wproj + k * 128);
            #pragma unroll 8
            for (int i4 = 0; i4 < 32; ++i4) {
                float4 wv = wr[i4];
                acc += wv.x * s_f[i4 * 4 + 0][e] + wv.y * s_f[i4 * 4 + 1][e] +
                       wv.z * s_f[i4 * 4 + 2][e] + wv.w * s_f[i4 * 4 + 3][e];
            }
        }
        BeObs[e * 512 + k] = f2bf(acc);
    } else {                               // blk==464: BeSub/BeNode/biasE/zeros
        __shared__ float s_f[128][8];
        for (int it = t; it < 1024; it += 256) {
            int i = it >> 3, e = it & 7, hd = e & 3;
            const float* av = ((e < 4) ? a_src1 : a_dst1) + hd * 32;
            float acc = 0.f;
            #pragma unroll
            for (int f = 0; f < 32; ++f) acc += W1[i * 128 + hd * 32 + f] * av[f];
            s_f[i][e] = acc;
        }
        __syncthreads();
        for (int it = t; it < 2048; it += 256) {
            int arr = it >> 10, rem = it & 1023;
            int e = rem >> 7, k = rem & 127, hd = e & 3;
            const float* av = ((e < 4) ? a_src1 : a_dst1) + hd * 32;
            int row = (arr ? 256 : 128) + k;
            float acc = 0.f;
            #pragma unroll
            for (int f = 0; f < 32; ++f) acc += W1[row * 128 + hd * 32 + f] * av[f];
            (arr ? BeNode : BeSub)[e * 128 + k] = f2bf(acc);
        }
        if (t < 8) {
            float acc = 0.f;
            for (int i = 0; i < 128; ++i) acc += bproj[i] * s_f[i][t];
            biasE[t] = acc;
        } else if (t < 16) {
            biasE[t] = 0.f;
        }
        for (int it = t; it < 6144; it += 256) {   // zero pad rows 8..15
            if (it < 4096) BeObs[4096 + it] = 0;
            else { int o = it - 4096; if (o < 1024) BeSub[1024 + o] = 0;
                   else BeNode[o] = 0; }
        }
    }
}

// ---------------------------------------------------------------------------
// Main: block = 16 batches, 9 waves. Waves 0-7: h-cols 16w..16w+15; wave 8:
// e-tile (es/ed per head via folded B). obs->obs_repr (K=512) -> bf16 LDS
// roundtrip -> @W1a (K=128); sub@W1b and nodes@W1c direct. All LDS tiles
// XOR-swizzled (byte ^= (row&7)<<4) -> conflict-free ds_read_b128.
// ---------------------------------------------------------------------------
__global__ void __launch_bounds__(NTHR) k_main(
    const float* __restrict__ org_obs, const float* __restrict__ node_emb,
    const float* __restrict__ subst,   const int* __restrict__ sub_choice,
    const int* __restrict__ sub_map,   const ushort_t* __restrict__ WprojT,
    const ushort_t* __restrict__ W1T,  const ushort_t* __restrict__ BeObs,
    const ushort_t* __restrict__ BeSub,const ushort_t* __restrict__ BeNode,
    const float* __restrict__ biasE,   const float* __restrict__ bproj,
    const float* __restrict__ b1,      const float* __restrict__ W2,
    const float* __restrict__ a_src2,  const float* __restrict__ a_dst2,
    const float* __restrict__ b2,      float* __restrict__ out) {

    // LDS map (bytes):
    //   s_a     @0      [16][640] bf16 swz  = 20480   (obs 0..499 | 0 | sub 512..639)
    //   s_nodes @20480  [6][16][128] bf16 swz = 24576
    //   s_x     @45056  [16][128] bf16 swz  = 4096    (bf16(obs_repr + bproj))
    //   s_e     @49152  [16][6][8] f32      = 3072    (cols 0-3 es, 4-7 ed)
    //   s_alpha @52224  f32[16*145]         = 9280    (b*145 + i*24 + hd*6 + j)
    //   s_p     @61504  f32[8][16][6]       = 3072
    __shared__ __align__(16) char smem[64576];
    float* s_e     = (float*)(smem + 49152);
    float* s_alpha = (float*)(smem + 52224);
    float* s_p     = (float*)(smem + 61504);

    const int t   = threadIdx.x;
    const int gb0 = blockIdx.x * TB;

    // ---- staging (waves 0-7): obs+sub -> s_a; nodes -> regs (write later)
    float4 nreg[6];
    if (t < 512) {
        const int b = t >> 5, l = t & 31;
        const float* orow = org_obs + (size_t)(gb0 + b) * OBSD;
        int sub = sub_choice[gb0 + b];
        const int* emap = sub_map + sub * KN;
        int eid[6];
        #pragma unroll
        for (int s = 0; s < 6; ++s) eid[s] = emap[s];
        #pragma unroll
        for (int s = 0; s < 6; ++s)
            nreg[s] = ((const float4*)(node_emb +
                        ((size_t)(gb0 + b) * NNODE + eid[s]) * HH))[l];
        const int swz = (b & 7) << 4;
        #pragma unroll
        for (int it = 0; it < 4; ++it) {
            int idx = it * 32 + l;
            u16x4 v = {0, 0, 0, 0};
            if (idx < 125) v = f2bf4(((const float4*)orow)[idx]);
            *(u16x4*)(smem + b * 1280 + ((idx * 8) ^ swz)) = v;
        }
        const float* srow = subst + ((size_t)(gb0 + b) * NSUB + sub) * HH;
        float4 sv = ((const float4*)srow)[l];
        *(u16x4*)(smem + b * 1280 + ((1024 + l * 8) ^ swz)) = f2bf4(sv);
    }
    __syncthreads();

    const int w = t >> 6, ln = t & 63, r16 = ln & 15, g = ln >> 4;
    const int col = w * 16 + r16;            // h-col (valid for w<8)
    const int rswz = (r16 & 7) << 4;

    const ushort_t* Bobs = (w < 8) ? (WprojT + col * 512) : (BeObs + r16 * 512);
    const ushort_t* Bsub = (w < 8) ? (W1T + col * 384 + 128) : (BeSub + r16 * 128);
    const ushort_t* Bv   = (w < 8) ? (W1T + col * 384 + 256) : (BeNode + r16 * 128);

    // ---- phase 1: obs-path (K=512) and sub-path (K=128)
    f32x4 acc1 = {0.f, 0.f, 0.f, 0.f}, acc2 = {0.f, 0.f, 0.f, 0.f};
    #pragma unroll
    for (int kk = 0; kk < 16; ++kk) {
        s16x8 af = *(const s16x8*)(smem + r16 * 1280 + ((kk * 64 + g * 16) ^ rswz));
        s16x8 bf = *(const s16x8*)&Bobs[kk * 32 + g * 8];
        acc1 = MFMA16(af, bf, acc1);
    }
    #pragma unroll
    for (int kk = 0; kk < 4; ++kk) {
        s16x8 af = *(const s16x8*)(smem + r16 * 1280 + ((1024 + kk * 64 + g * 16) ^ rswz));
        s16x8 bf = *(const s16x8*)&Bsub[kk * 32 + g * 8];
        acc2 = MFMA16(af, bf, acc2);
    }

    // ---- obs_repr (+bproj) -> s_x (bf16); nodes regs -> s_nodes
    if (w < 8) {
        float bp = bproj[col];
        #pragma unroll
        for (int rg = 0; rg < 4; ++rg) {
            int bb = g * 4 + rg;
            *(ushort_t*)(smem + 45056 + bb * 256 + ((col * 2) ^ ((bb & 7) << 4))) =
                f2bf(acc1[rg] + bp);
        }
    }
    if (t < 512) {
        const int b = t >> 5, l = t & 31;
        const int swz = (b & 7) << 4;
        #pragma unroll
        for (int s = 0; s < 6; ++s)
            *(u16x4*)(smem + 20480 + (s * 16 + b) * 256 + ((l * 8) ^ swz)) =
                f2bf4(nreg[s]);
    }
    __syncthreads();

    // ---- U2: obs_repr @ W1a (w<8 only), K=128
    f32x4 u2 = {0.f, 0.f, 0.f, 0.f};
    if (w < 8) {
        #pragma unroll
        for (int kk = 0; kk < 4; ++kk) {
            s16x8 af = *(const s16x8*)(smem + 45056 + r16 * 256 + ((kk * 64 + g * 16) ^ rswz));
            s16x8 bf = *(const s16x8*)&W1T[col * 384 + kk * 32 + g * 8];
            u2 = MFMA16(af, bf, u2);
        }
    }

    // ---- V: nodes @ W1c (w<8) / @ BeNode (w8), K=128, 6 nodes
    f32x4 v[6];
    #pragma unroll
    for (int s = 0; s < 6; ++s) v[s] = (f32x4){0.f, 0.f, 0.f, 0.f};
    #pragma unroll
    for (int kk = 0; kk < 4; ++kk) {
        s16x8 bf = *(const s16x8*)&Bv[kk * 32 + g * 8];
        #pragma unroll
        for (int s = 0; s < 6; ++s) {
            s16x8 af = *(const s16x8*)(smem + 20480 + (s * 16 + r16) * 256 +
                                       ((kk * 64 + g * 16) ^ rswz));
            v[s] = MFMA16(af, bf, v[s]);
        }
    }

    // h fragments (w<8); e-values -> s_e (w8)
    float h[6][4];
    if (w < 8) {
        #pragma unroll
        for (int s = 0; s < 6; ++s)
            #pragma unroll
            for (int rg = 0; rg < 4; ++rg)
                h[s][rg] = u2[rg] + acc2[rg] + v[s][rg];
    } else if (r16 < 8) {
        float be = biasE[r16];
        #pragma unroll
        for (int s = 0; s < 6; ++s)
            #pragma unroll
            for (int rg = 0; rg < 4; ++rg)
                s_e[((g * 4 + rg) * 6 + s) * 8 + r16] =
                    acc1[rg] + acc2[rg] + v[s][rg] + be;
    }
    __syncthreads();

    // ---- layer-1 alphas: 384 threads, one softmax-6 each
    if (t < 384) {
        int hd = t & 3, i = (t >> 2) % 6, b = t / 24;
        float ed = s_e[(b * 6 + i) * 8 + 4 + hd];
        float ev[6], mx = -1e30f;
        #pragma unroll
        for (int j = 0; j < 6; ++j) {
            float e = ed + s_e[(b * 6 + j) * 8 + hd];
            e = (e > 0.f) ? e : 0.2f * e;
            ev[j] = e; mx = fmaxf(mx, e);
        }
        float ex[6], ss = 0.f;
        #pragma unroll
        for (int j = 0; j < 6; ++j) { ex[j] = __expf(ev[j] - mx); ss += ex[j]; }
        float inv = 1.f / ss;
        #pragma unroll
        for (int j = 0; j < 6; ++j)
            s_alpha[b * 145 + i * 24 + hd * 6 + j] = ex[j] * inv;
    }
    __syncthreads();

    // ---- aggregation + b1 + ELU + *W2 + 16-lane reduce -> s_p
    if (w < 8) {
        const int hd = w >> 1;
        float b1v = b1[col], w2v = W2[col];
        #pragma unroll
        for (int i = 0; i < 6; ++i)
            #pragma unroll
            for (int rg = 0; rg < 4; ++rg) {
                int bb = g * 4 + rg;
                const float* al = s_alpha + bb * 145 + i * 24 + hd * 6;
                float acc = al[0] * h[0][rg] + al[1] * h[1][rg] + al[2] * h[2][rg] +
                            al[3] * h[3][rg] + al[4] * h[4][rg] + al[5] * h[5][rg];
                float o = acc + b1v;
                o = (o > 0.f) ? o : __expf(o) - 1.f;   // ELU
                float p = o * w2v;
                p += __shfl_xor(p, 1); p += __shfl_xor(p, 2);
                p += __shfl_xor(p, 4); p += __shfl_xor(p, 8);
                if (r16 == 0) s_p[(w * 16 + bb) * 6 + i] = p;
            }
    }
    __syncthreads();

    // ---- combine h2 + layer-2 GAT (redundant hh per thread, no extra sync)
    if (t < 96) {
        int b = t / 6, i = t - b * 6;
        float hh[6];
        #pragma unroll
        for (int j = 0; j < 6; ++j) {
            float acc = 0.f;
            #pragma unroll
            for (int ww = 0; ww < 8; ++ww) acc += s_p[(ww * 16 + b) * 6 + j];
            hh[j] = acc;
        }
        float as2v = a_src2[0], ad2v = a_dst2[0];
        float hi = hh[i];
        float ev[6], mx = -1e30f;
        #pragma unroll
        for (int j = 0; j < 6; ++j) {
            float e = ad2v * hi + as2v * hh[j];
            e = (e > 0.f) ? e : 0.2f * e;
            ev[j] = e; mx = fmaxf(mx, e);
        }
        float ss = 0.f, acc = 0.f;
        #pragma unroll
        for (int j = 0; j < 6; ++j) {
            float ex = __expf(ev[j] - mx);
            ss += ex; acc += ex * hh[j];
        }
        out[(gb0 + b) * 6 + i] = acc / ss + b2[0];
    }
}

extern "C" void kernel_launch(void* const* d_in, const int* in_sizes, int n_in,
                              void* d_out, int out_size, void* d_ws, size_t ws_size,
                              hipStream_t stream) {
    const float* org_obs    = (const float*)d_in[0];
    const float* node_emb   = (const float*)d_in[1];
    const float* subst      = (const float*)d_in[2];
    const int*   sub_choice = (const int*)d_in[3];
    const int*   sub_map    = (const int*)d_in[4];
    const float* Wproj      = (const float*)d_in[5];
    const float* bproj      = (const float*)d_in[6];
    const float* W1         = (const float*)d_in[7];
    const float* a_src1     = (const float*)d_in[8];
    const float* a_dst1     = (const float*)d_in[9];
    const float* b1         = (const float*)d_in[10];
    const float* W2         = (const float*)d_in[11];
    const float* a_src2     = (const float*)d_in[12];
    const float* a_dst2     = (const float*)d_in[13];
    const float* b2         = (const float*)d_in[14];

    ushort_t* WprojT = (ushort_t*)((char*)d_ws + WS_WPROJT);
    ushort_t* W1T    = (ushort_t*)((char*)d_ws + WS_W1T);
    ushort_t* BeObs  = (ushort_t*)((char*)d_ws + WS_BEOBS);
    ushort_t* BeSub  = (ushort_t*)((char*)d_ws + WS_BESUB);
    ushort_t* BeNode = (ushort_t*)((char*)d_ws + WS_BENODE);
    float*    biasE  = (float*)((char*)d_ws + WS_BIASE);

    hipLaunchKernelGGL(k_prep, dim3(465), dim3(256), 0, stream,
                       Wproj, bproj, W1, a_src1, a_dst1,
                       WprojT, W1T, BeObs, BeSub, BeNode, biasE);
    hipLaunchKernelGGL(k_main, dim3(BB / TB), dim3(NTHR), 0, stream,
                       org_obs, node_emb, subst, sub_choice, sub_map,
                       WprojT, W1T, BeObs, BeSub, BeNode, biasE, bproj,
                       b1, W2, a_src2, a_dst2, b2, (float*)d_out);
}

// Round 4
// 23.602 us; speedup vs baseline: 1.8097x; 1.8097x over previous
//
#include <hip/hip_runtime.h>

// Problem constants
#define BB     4096
#define NNODE  177
#define NSUB   36
#define KN     6
#define HH     128
#define OBSD   500
#define TB     16          // batches per block = MFMA M (all rows real)
#define NTHR   512         // 8 waves, balanced 2/SIMD

typedef unsigned short ushort_t;
typedef __attribute__((ext_vector_type(4))) float f32x4;
typedef __attribute__((ext_vector_type(8))) short s16x8;
typedef __attribute__((ext_vector_type(4))) unsigned short u16x4;

#define MFMA16(a, b, c) __builtin_amdgcn_mfma_f32_16x16x32_bf16((a), (b), (c), 0, 0, 0)

__device__ __forceinline__ ushort_t f2bf(float f) {
    unsigned u = __float_as_uint(f);
    u += 0x7FFFu + ((u >> 16) & 1u);   // RNE
    return (ushort_t)(u >> 16);
}
__device__ __forceinline__ u16x4 f2bf4(float4 v) {
    u16x4 o; o.x = f2bf(v.x); o.y = f2bf(v.y); o.z = f2bf(v.z); o.w = f2bf(v.w);
    return o;
}

// B-fragment on the fly: bf16x8 of W[(k+j)*128 + col], j=0..7 (column slice,
// 16 lanes of a g-group hit one 64B L2 line per j). RNE via v_cvt_pk_bf16_f32.
__device__ __forceinline__ s16x8 ldB8(const float* __restrict__ W, int k, int col) {
    const float* p = W + k * HH + col;
    float w0 = p[0],      w1 = p[HH],     w2 = p[2 * HH], w3 = p[3 * HH];
    float w4 = p[4 * HH], w5 = p[5 * HH], w6 = p[6 * HH], w7 = p[7 * HH];
    union { unsigned u[4]; s16x8 v; } U;
    asm("v_cvt_pk_bf16_f32 %0, %1, %2" : "=v"(U.u[0]) : "v"(w0), "v"(w1));
    asm("v_cvt_pk_bf16_f32 %0, %1, %2" : "=v"(U.u[1]) : "v"(w2), "v"(w3));
    asm("v_cvt_pk_bf16_f32 %0, %1, %2" : "=v"(U.u[2]) : "v"(w4), "v"(w5));
    asm("v_cvt_pk_bf16_f32 %0, %1, %2" : "=v"(U.u[3]) : "v"(w6), "v"(w7));
    return U.v;
}
__device__ __forceinline__ s16x8 ldB8m(const float* __restrict__ W, int k, int col, int kmax) {
    float w[8];
    #pragma unroll
    for (int j = 0; j < 8; ++j) w[j] = (k + j < kmax) ? W[(k + j) * HH + col] : 0.f;
    union { unsigned u[4]; s16x8 v; } U;
    #pragma unroll
    for (int j = 0; j < 4; ++j)
        asm("v_cvt_pk_bf16_f32 %0, %1, %2" : "=v"(U.u[j]) : "v"(w[2 * j]), "v"(w[2 * j + 1]));
    return U.v;
}

// ---------------------------------------------------------------------------
// Single fused kernel. Block = 16 batches, 8 waves; wave w owns cols
// [16w, 16w+16). Weights are consumed directly from f32 global (L2-hot),
// converted to bf16 fragments in-register — no prep kernel.
//   phase1: obs@Wproj (K=512, masked tail) -> obs_repr(+bproj) -> s_x bf16
//   U2: s_x@W1a; sub@W1b; V: nodes@W1c (K=128 each) -> h fragments
//   h -> s_h f32; es/ed from s_h (384 dots); alphas; aggregation (reg h);
//   layer-2 GAT scalar.
// ---------------------------------------------------------------------------
__global__ void __launch_bounds__(NTHR, 2) k_main(
    const float* __restrict__ org_obs, const float* __restrict__ node_emb,
    const float* __restrict__ subst,   const int* __restrict__ sub_choice,
    const int* __restrict__ sub_map,   const float* __restrict__ Wproj,
    const float* __restrict__ bproj,   const float* __restrict__ W1,
    const float* __restrict__ a_src1,  const float* __restrict__ a_dst1,
    const float* __restrict__ b1,      const float* __restrict__ W2,
    const float* __restrict__ a_src2,  const float* __restrict__ a_dst2,
    const float* __restrict__ b2,      float* __restrict__ out) {

    // LDS map (bytes):
    //   s_a     @0      [16][640] bf16 swz   = 20480  (obs 0..499|0|sub 512..639)
    //   s_nodes @20480  [6][16][128] bf16 swz = 24576
    //   s_x     @45056  [16][128] bf16 swz   =  4096
    //   s_h     @49152  [16][6][128] f32     = 49152
    //   s_e     @98304  [16][6][8] f32       =  3072  (0-3 es, 4-7 ed)
    //   s_alpha @101376 f32[16*145]          =  9280
    //   s_p     @110656 f32[8][16][6]        =  3072
    __shared__ __align__(16) char smem[113728];
    float* s_h     = (float*)(smem + 49152);
    float* s_e     = (float*)(smem + 98304);
    float* s_alpha = (float*)(smem + 101376);
    float* s_p     = (float*)(smem + 110656);

    const int t   = threadIdx.x;
    const int gb0 = blockIdx.x * TB;

    // ---- staging: obs+sub -> s_a (swz); nodes -> regs (write after phase1)
    float4 nreg[6];
    {
        const int b = t >> 5, l = t & 31;
        const float* orow = org_obs + (size_t)(gb0 + b) * OBSD;
        int sub = sub_choice[gb0 + b];
        const int* emap = sub_map + sub * KN;
        #pragma unroll
        for (int s = 0; s < 6; ++s)
            nreg[s] = ((const float4*)(node_emb +
                        ((size_t)(gb0 + b) * NNODE + emap[s]) * HH))[l];
        const int swz = (b & 7) << 4;
        #pragma unroll
        for (int it = 0; it < 4; ++it) {
            int idx = it * 32 + l;
            u16x4 v = {0, 0, 0, 0};
            if (idx < 125) v = f2bf4(((const float4*)orow)[idx]);
            *(u16x4*)(smem + b * 1280 + ((idx * 8) ^ swz)) = v;
        }
        const float* srow = subst + ((size_t)(gb0 + b) * NSUB + sub) * HH;
        *(u16x4*)(smem + b * 1280 + ((1024 + l * 8) ^ swz)) = f2bf4(((const float4*)srow)[l]);
    }
    __syncthreads();

    const int w = t >> 6, ln = t & 63, r16 = ln & 15, g = ln >> 4;
    const int col = w * 16 + r16;
    const int rswz = (r16 & 7) << 4;

    // ---- phase 1: obs @ Wproj (K=512, rows 500..511 masked)
    f32x4 acc1 = {0.f, 0.f, 0.f, 0.f};
    #pragma unroll 5
    for (int kk = 0; kk < 15; ++kk) {
        s16x8 af = *(const s16x8*)(smem + r16 * 1280 + ((kk * 64 + g * 16) ^ rswz));
        s16x8 bf = ldB8(Wproj, kk * 32 + g * 8, col);
        acc1 = MFMA16(af, bf, acc1);
    }
    {
        s16x8 af = *(const s16x8*)(smem + r16 * 1280 + ((15 * 64 + g * 16) ^ rswz));
        s16x8 bf = ldB8m(Wproj, 15 * 32 + g * 8, col, OBSD);
        acc1 = MFMA16(af, bf, acc1);
    }

    // ---- obs_repr(+bproj) -> s_x bf16; node regs -> s_nodes
    {
        float bp = bproj[col];
        #pragma unroll
        for (int rg = 0; rg < 4; ++rg) {
            int bb = g * 4 + rg;
            *(ushort_t*)(smem + 45056 + bb * 256 + ((col * 2) ^ ((bb & 7) << 4))) =
                f2bf(acc1[rg] + bp);
        }
    }
    {
        const int b = t >> 5, l = t & 31;
        const int swz = (b & 7) << 4;
        #pragma unroll
        for (int s = 0; s < 6; ++s)
            *(u16x4*)(smem + 20480 + (s * 16 + b) * 256 + ((l * 8) ^ swz)) =
                f2bf4(nreg[s]);
    }
    __syncthreads();

    // ---- U2: obs_repr @ W1a (rows 0..127) + sub @ W1b (rows 128..255)
    f32x4 u2 = {0.f, 0.f, 0.f, 0.f}, acc2 = {0.f, 0.f, 0.f, 0.f};
    #pragma unroll
    for (int kk = 0; kk < 4; ++kk) {
        s16x8 afx = *(const s16x8*)(smem + 45056 + r16 * 256 + ((kk * 64 + g * 16) ^ rswz));
        s16x8 bfx = ldB8(W1, kk * 32 + g * 8, col);
        u2 = MFMA16(afx, bfx, u2);
        s16x8 afs = *(const s16x8*)(smem + r16 * 1280 + ((1024 + kk * 64 + g * 16) ^ rswz));
        s16x8 bfs = ldB8(W1 + 128 * HH, kk * 32 + g * 8, col);
        acc2 = MFMA16(afs, bfs, acc2);
    }

    // ---- V: nodes @ W1c (rows 256..383), B reused across 6 nodes
    f32x4 v[6];
    #pragma unroll
    for (int s = 0; s < 6; ++s) v[s] = (f32x4){0.f, 0.f, 0.f, 0.f};
    #pragma unroll
    for (int kk = 0; kk < 4; ++kk) {
        s16x8 bf = ldB8(W1 + 256 * HH, kk * 32 + g * 8, col);
        #pragma unroll
        for (int s = 0; s < 6; ++s) {
            s16x8 af = *(const s16x8*)(smem + 20480 + (s * 16 + r16) * 256 +
                                       ((kk * 64 + g * 16) ^ rswz));
            v[s] = MFMA16(af, bf, v[s]);
        }
    }

    // ---- h fragments + write s_h (f32) for e computation
    float h[6][4];
    #pragma unroll
    for (int s = 0; s < 6; ++s)
        #pragma unroll
        for (int rg = 0; rg < 4; ++rg) {
            h[s][rg] = u2[rg] + acc2[rg] + v[s][rg];
            s_h[((g * 4 + rg) * 6 + s) * 128 + col] = h[s][rg];
        }
    __syncthreads();

    // ---- es/ed: 384 threads, two 32-MAC dots each (a-vectors L2-hot)
    if (t < 384) {
        int b = t / 24, rem = t - b * 24, i = rem >> 2, hd = rem & 3;
        const float* hrow = s_h + (b * 6 + i) * 128 + hd * 32;
        const float* as = a_src1 + hd * 32;
        const float* ad = a_dst1 + hd * 32;
        float ps = 0.f, pd = 0.f;
        #pragma unroll
        for (int f = 0; f < 32; ++f) {
            float hv = hrow[f];
            ps += hv * as[f];
            pd += hv * ad[f];
        }
        s_e[(b * 6 + i) * 8 + hd]     = ps;
        s_e[(b * 6 + i) * 8 + 4 + hd] = pd;
    }
    __syncthreads();

    // ---- layer-1 alphas: 384 threads, one softmax-6 each
    if (t < 384) {
        int b = t / 24, rem = t - b * 24, i = rem >> 2, hd = rem & 3;
        float ed = s_e[(b * 6 + i) * 8 + 4 + hd];
        float ev[6], mx = -1e30f;
        #pragma unroll
        for (int j = 0; j < 6; ++j) {
            float e = ed + s_e[(b * 6 + j) * 8 + hd];
            e = (e > 0.f) ? e : 0.2f * e;
            ev[j] = e; mx = fmaxf(mx, e);
        }
        float ex[6], ss = 0.f;
        #pragma unroll
        for (int j = 0; j < 6; ++j) { ex[j] = __expf(ev[j] - mx); ss += ex[j]; }
        float inv = 1.f / ss;
        #pragma unroll
        for (int j = 0; j < 6; ++j)
            s_alpha[b * 145 + i * 24 + hd * 6 + j] = ex[j] * inv;
    }
    __syncthreads();

    // ---- aggregation (reg h) + b1 + ELU + *W2 + 16-lane reduce -> s_p
    {
        const int hd = w >> 1;
        float b1v = b1[col], w2v = W2[col];
        #pragma unroll
        for (int i = 0; i < 6; ++i)
            #pragma unroll
            for (int rg = 0; rg < 4; ++rg) {
                int bb = g * 4 + rg;
                const float* al = s_alpha + bb * 145 + i * 24 + hd * 6;
                float acc = al[0] * h[0][rg] + al[1] * h[1][rg] + al[2] * h[2][rg] +
                            al[3] * h[3][rg] + al[4] * h[4][rg] + al[5] * h[5][rg];
                float o = acc + b1v;
                o = (o > 0.f) ? o : __expf(o) - 1.f;   // ELU
                float p = o * w2v;
                p += __shfl_xor(p, 1); p += __shfl_xor(p, 2);
                p += __shfl_xor(p, 4); p += __shfl_xor(p, 8);
                if (r16 == 0) s_p[(w * 16 + bb) * 6 + i] = p;
            }
    }
    __syncthreads();

    // ---- combine h2 + layer-2 GAT + write
    if (t < 96) {
        int b = t / 6, i = t - b * 6;
        float hh[6];
        #pragma unroll
        for (int j = 0; j < 6; ++j) {
            float acc = 0.f;
            #pragma unroll
            for (int ww = 0; ww < 8; ++ww) acc += s_p[(ww * 16 + b) * 6 + j];
            hh[j] = acc;
        }
        float as2v = a_src2[0], ad2v = a_dst2[0];
        float hi = hh[i];
        float ev[6], mx = -1e30f;
        #pragma unroll
        for (int j = 0; j < 6; ++j) {
            float e = ad2v * hi + as2v * hh[j];
            e = (e > 0.f) ? e : 0.2f * e;
            ev[j] = e; mx = fmaxf(mx, e);
        }
        float ss = 0.f, acc = 0.f;
        #pragma unroll
        for (int j = 0; j < 6; ++j) {
            float ex = __expf(ev[j] - mx);
            ss += ex; acc += ex * hh[j];
        }
        out[(gb0 + b) * 6 + i] = acc / ss + b2[0];
    }
}

extern "C" void kernel_launch(void* const* d_in, const int* in_sizes, int n_in,
                              void* d_out, int out_size, void* d_ws, size_t ws_size,
                              hipStream_t stream) {
    const float* org_obs    = (const float*)d_in[0];
    const float* node_emb   = (const float*)d_in[1];
    const float* subst      = (const float*)d_in[2];
    const int*   sub_choice = (const int*)d_in[3];
    const int*   sub_map    = (const int*)d_in[4];
    const float* Wproj      = (const float*)d_in[5];
    const float* bproj      = (const float*)d_in[6];
    const float* W1         = (const float*)d_in[7];
    const float* a_src1     = (const float*)d_in[8];
    const float* a_dst1     = (const float*)d_in[9];
    const float* b1         = (const float*)d_in[10];
    const float* W2         = (const float*)d_in[11];
    const float* a_src2     = (const float*)d_in[12];
    const float* a_dst2     = (const float*)d_in[13];
    const float* b2         = (const float*)d_in[14];

    hipLaunchKernelGGL(k_main, dim3(BB / TB), dim3(NTHR), 0, stream,
                       org_obs, node_emb, subst, sub_choice, sub_map,
                       Wproj, bproj, W1, a_src1, a_dst1, b1, W2,
                       a_src2, a_dst2, b2, (float*)d_out);
}